// Round 5
// baseline (1543.848 us; speedup 1.0000x reference)
//
#include <hip/hip_runtime.h>

// Problem constants: B=16, S=1024, d=1024, H=16, dh=64
#define B_  16
#define S_  1024
#define D_  1024
#define H_  16
#define DH_ 64
#define M_  (B_ * S_)
#define BH_ (B_ * H_)

typedef __attribute__((ext_vector_type(8))) __bf16 bf16x8;
typedef __attribute__((ext_vector_type(4))) float  f32x4;

__device__ __forceinline__ ushort f2bf(float f) {
  unsigned u = __builtin_bit_cast(unsigned, f);
  return (ushort)((u + 0x7FFFu + ((u >> 16) & 1u)) >> 16);
}

__device__ __forceinline__ bf16x8 ld8(const ushort* p) {
  return *(const bf16x8*)p;
}

__device__ __forceinline__ float fast_exp2(float x) {
  return __builtin_amdgcn_exp2f(x);
}

__device__ __forceinline__ void gl_lds16(const void* g, void* s) {
  __builtin_amdgcn_global_load_lds((__attribute__((address_space(1))) void*)g,
                                   (__attribute__((address_space(3))) void*)s,
                                   16, 0, 0);
}

__device__ __forceinline__ uint pack2(float a, float b) {
  return (uint)f2bf(a) | ((uint)f2bf(b) << 16);
}

// ---------------------------------------------------------------- fp32->bf16
__global__ void cvt4(const float* __restrict__ s, ushort* __restrict__ d, int n4) {
  int i = blockIdx.x * 256 + threadIdx.x;
  if (i < n4) {
    const float4 v = ((const float4*)s)[i];
    ushort4 o;
    o.x = f2bf(v.x); o.y = f2bf(v.y); o.z = f2bf(v.z); o.w = f2bf(v.w);
    ((ushort4*)d)[i] = o;
  }
}

// All four weight matrices in one launch; dst buffers are contiguous (wq|wk|wv|wo).
__global__ void cvtW(const float* __restrict__ s0, const float* __restrict__ s1,
                     const float* __restrict__ s2, const float* __restrict__ s3,
                     ushort* __restrict__ d) {
  int i = blockIdx.x * 256 + threadIdx.x;       // 0 .. 4*262144-1 (float4 units)
  const int j = i >> 18;                        // which weight
  const float* s = (j == 0) ? s0 : (j == 1) ? s1 : (j == 2) ? s2 : s3;
  const float4 v = ((const float4*)s)[i & 262143];
  ushort4 o;
  o.x = f2bf(v.x); o.y = f2bf(v.y); o.z = f2bf(v.z); o.w = f2bf(v.w);
  ((ushort4*)d)[i] = o;
}

// ------------------------------------------------------- fused QKV projection
// One GEMM over concatenated Wqkv [3072,1024]. Operand order chosen per
// projection so the 4 acc regs are consecutive OUTPUT elements:
//   proj 0/1 (Q,K -> [B,H,S,dh]): mfma(B,A): regs = n (dc contiguous) -> uint2
//   proj 2   (V  -> [B,H,dh,S]):  mfma(A,B): regs = m (s contiguous)  -> uint2
__global__ void gemm_qkv(const ushort* __restrict__ A, const ushort* __restrict__ Wqkv,
                         const float* __restrict__ bqp, const float* __restrict__ bkp,
                         const float* __restrict__ bvp, ushort* __restrict__ qO,
                         ushort* __restrict__ kO, ushort* __restrict__ vtO) {
  __shared__ ushort lA[128 * 32];
  __shared__ ushort lB[128 * 32];
  const int w  = threadIdx.x >> 6;
  const int l  = threadIdx.x & 63;
  const int m0 = blockIdx.y * 128, n0 = blockIdx.x * 128;
  const int srow = (w << 4) + (l >> 2);
  const int scol = (l & 3) << 3;
  const int lr = l & 15, qd = l >> 4;
  const int wm = (w >> 1) << 6, wn = (w & 1) << 6;
  const int K = D_;
  const int proj = n0 >> 10;            // block-uniform 0/1/2
  const bool swp = (proj < 2);

  const f32x4 z = {0.f, 0.f, 0.f, 0.f};
  f32x4 acc[4][4];                      // [m-tile][n-tile]
#pragma unroll
  for (int i = 0; i < 4; i++)
#pragma unroll
    for (int j = 0; j < 4; j++) acc[i][j] = z;

  for (int k0 = 0; k0 < K; k0 += 32) {
#pragma unroll
    for (int r = 0; r < 2; r++) {
      const int row = r * 64 + srow;
      gl_lds16(A    + (size_t)(m0 + row) * K + k0 + scol, &lA[row * 32 + scol]);
      gl_lds16(Wqkv + (size_t)(n0 + row) * K + k0 + scol, &lB[row * 32 + scol]);
    }
    __syncthreads();
    bf16x8 af[4], bf_[4];
#pragma unroll
    for (int t = 0; t < 4; t++) {
      af[t]  = ld8(&lA[(wm + t * 16 + lr) * 32 + qd * 8]);
      bf_[t] = ld8(&lB[(wn + t * 16 + lr) * 32 + qd * 8]);
    }
    if (swp) {
#pragma unroll
      for (int i = 0; i < 4; i++)
#pragma unroll
        for (int j = 0; j < 4; j++)
          acc[i][j] = __builtin_amdgcn_mfma_f32_16x16x32_bf16(bf_[j], af[i], acc[i][j], 0, 0, 0);
    } else {
#pragma unroll
      for (int i = 0; i < 4; i++)
#pragma unroll
        for (int j = 0; j < 4; j++)
          acc[i][j] = __builtin_amdgcn_mfma_f32_16x16x32_bf16(af[i], bf_[j], acc[i][j], 0, 0, 0);
    }
    __syncthreads();
  }

  const int nb = n0 & 1023;
  if (swp) {
    // regs = n (dc), col(lr) = m (s)
    const float* bias = (proj == 0) ? bqp : bkp;
    ushort* outH = (proj == 0) ? qO : kO;
#pragma unroll
    for (int j = 0; j < 4; j++) {
      const int n = nb + wn + j * 16 + qd * 4;
      const float4 b4 = *(const float4*)(bias + n);
      const int h = n >> 6, dc = n & 63;
#pragma unroll
      for (int i = 0; i < 4; i++) {
        const int m = m0 + wm + i * 16 + lr;
        const int b = m >> 10, s = m & 1023;
        const f32x4 v = acc[i][j];
        uint2 pk;
        pk.x = pack2(v[0] + b4.x, v[1] + b4.y);
        pk.y = pack2(v[2] + b4.z, v[3] + b4.w);
        *(uint2*)(outH + ((size_t)(b * H_ + h) * S_ + s) * DH_ + dc) = pk;
      }
    }
  } else {
    // regs = m (s), col(lr) = n (dc)
#pragma unroll
    for (int j = 0; j < 4; j++) {
      const int n = nb + wn + j * 16 + lr;
      const float bv = bvp[n];
      const int h = n >> 6, dc = n & 63;
#pragma unroll
      for (int i = 0; i < 4; i++) {
        const int mb = m0 + wm + i * 16 + qd * 4;
        const int b = mb >> 10, s = mb & 1023;
        const f32x4 v = acc[i][j];
        uint2 pk;
        pk.x = pack2(v[0] + bv, v[1] + bv);
        pk.y = pack2(v[2] + bv, v[3] + bv);
        *(uint2*)(vtO + ((size_t)(b * H_ + h) * DH_ + dc) * S_ + s) = pk;
      }
    }
  }
}

// ------------------------------------------------------------- output GEMM
// Swapped operands: regs = n -> float4 stores to fp32 out[m,n].
__global__ void gemm_out(const ushort* __restrict__ A, const ushort* __restrict__ W,
                         const float* __restrict__ bias, float* __restrict__ outF) {
  __shared__ ushort lA[128 * 32];
  __shared__ ushort lB[128 * 32];
  const int w  = threadIdx.x >> 6;
  const int l  = threadIdx.x & 63;
  const int m0 = blockIdx.y * 128, n0 = blockIdx.x * 128;
  const int srow = (w << 4) + (l >> 2);
  const int scol = (l & 3) << 3;
  const int lr = l & 15, qd = l >> 4;
  const int wm = (w >> 1) << 6, wn = (w & 1) << 6;
  const int K = D_, N = D_;

  const f32x4 z = {0.f, 0.f, 0.f, 0.f};
  f32x4 acc[4][4];
#pragma unroll
  for (int i = 0; i < 4; i++)
#pragma unroll
    for (int j = 0; j < 4; j++) acc[i][j] = z;

  for (int k0 = 0; k0 < K; k0 += 32) {
#pragma unroll
    for (int r = 0; r < 2; r++) {
      const int row = r * 64 + srow;
      gl_lds16(A + (size_t)(m0 + row) * K + k0 + scol, &lA[row * 32 + scol]);
      gl_lds16(W + (size_t)(n0 + row) * K + k0 + scol, &lB[row * 32 + scol]);
    }
    __syncthreads();
    bf16x8 af[4], bf_[4];
#pragma unroll
    for (int t = 0; t < 4; t++) {
      af[t]  = ld8(&lA[(wm + t * 16 + lr) * 32 + qd * 8]);
      bf_[t] = ld8(&lB[(wn + t * 16 + lr) * 32 + qd * 8]);
    }
#pragma unroll
    for (int i = 0; i < 4; i++)
#pragma unroll
      for (int j = 0; j < 4; j++)
        acc[i][j] = __builtin_amdgcn_mfma_f32_16x16x32_bf16(bf_[j], af[i], acc[i][j], 0, 0, 0);
    __syncthreads();
  }

#pragma unroll
  for (int j = 0; j < 4; j++) {
    const int n = n0 + wn + j * 16 + qd * 4;
    const float4 b4 = *(const float4*)(bias + n);
#pragma unroll
    for (int i = 0; i < 4; i++) {
      const int m = m0 + wm + i * 16 + lr;
      const f32x4 v = acc[i][j];
      float4 st;
      st.x = v[0] + b4.x; st.y = v[1] + b4.y;
      st.z = v[2] + b4.z; st.w = v[3] + b4.w;
      *(float4*)(outF + (size_t)m * N + n) = st;
    }
  }
}

// --------------------------------------------------------------- attention
// Barrier-free causal flash attention, transposed-score formulation, 32-row
// q-tiles with balanced pairing: wave p handles tiles p and 31-p (k-iters
// (p+1)+(32-p) = 33 for every wave). Grid (4, BH) = 1024 blocks = 4/CU
// co-resident -> 16 waves/CU.
#define PSTR 40
__global__ __launch_bounds__(256) void attn_kernel(
    const ushort* __restrict__ Q, const ushort* __restrict__ K,
    const ushort* __restrict__ Vt, ushort* __restrict__ O) {
  __shared__ ushort lP[4][32 * PSTR];
  const int bh = blockIdx.y;
  const int w = threadIdx.x >> 6, l = threadIdx.x & 63;
  const int lr = l & 15, qd = l >> 4;
  const int p = blockIdx.x * 4 + w;  // 0..15
  const size_t base = (size_t)bh * (S_ * DH_);
  const ushort* Qb = Q + base;
  const ushort* Kb = K + base;
  const ushort* Vb = Vt + (size_t)bh * (DH_ * S_);
  ushort* myP = &lP[w][0];
  const int b = bh >> 4, h = bh & 15;
  const float C = 0.18033688011112042f;  // log2(e) / sqrt(dh)
  const f32x4 z = {0.f, 0.f, 0.f, 0.f};

#pragma unroll 1
  for (int tt = 0; tt < 2; tt++) {
    const int q0 = (tt == 0 ? p : 31 - p) * 32;

    bf16x8 bq[2][2];
#pragma unroll
    for (int qt = 0; qt < 2; qt++)
#pragma unroll
      for (int kc = 0; kc < 2; kc++)
        bq[qt][kc] = ld8(Qb + (size_t)(q0 + qt * 16 + lr) * DH_ + kc * 32 + qd * 8);

    f32x4 acc[4][2];  // [dh tile][q tile], O^T C-layout
#pragma unroll
    for (int i = 0; i < 4; i++)
#pragma unroll
      for (int j = 0; j < 2; j++) acc[i][j] = z;
    float li[2] = {0.f, 0.f};

    for (int kb = 0; kb < q0 + 32; kb += 32) {
      bf16x8 ak[2][2];
#pragma unroll
      for (int kt = 0; kt < 2; kt++)
#pragma unroll
        for (int kc = 0; kc < 2; kc++)
          ak[kt][kc] = ld8(Kb + (size_t)(kb + kt * 16 + lr) * DH_ + kc * 32 + qd * 8);
      bf16x8 av[4];
#pragma unroll
      for (int dt = 0; dt < 4; dt++)
        av[dt] = ld8(Vb + (size_t)(dt * 16 + lr) * S_ + kb + qd * 8);

      const bool diag = (kb + 31 >= q0);  // wave-uniform (last iter only)
#pragma unroll
      for (int kt = 0; kt < 2; kt++) {
        const int keyb = kb + kt * 16 + qd * 4;
#pragma unroll
        for (int qt = 0; qt < 2; qt++) {
          f32x4 s = z;
          s = __builtin_amdgcn_mfma_f32_16x16x32_bf16(ak[kt][0], bq[qt][0], s, 0, 0, 0);
          s = __builtin_amdgcn_mfma_f32_16x16x32_bf16(ak[kt][1], bq[qt][1], s, 0, 0, 0);
          const int qq = q0 + qt * 16 + lr;
          float e0 = s[0] * C, e1 = s[1] * C, e2 = s[2] * C, e3 = s[3] * C;
          if (diag) {
            e0 = (keyb + 0 <= qq) ? e0 : -1e30f;
            e1 = (keyb + 1 <= qq) ? e1 : -1e30f;
            e2 = (keyb + 2 <= qq) ? e2 : -1e30f;
            e3 = (keyb + 3 <= qq) ? e3 : -1e30f;
          }
          const float p0 = fast_exp2(e0), p1 = fast_exp2(e1);
          const float p2 = fast_exp2(e2), p3 = fast_exp2(e3);
          li[qt] += (p0 + p1) + (p2 + p3);
          const uint d0 = __builtin_amdgcn_perm(__builtin_bit_cast(uint, p1),
                                                __builtin_bit_cast(uint, p0), 0x07060302u);
          const uint d1 = __builtin_amdgcn_perm(__builtin_bit_cast(uint, p3),
                                                __builtin_bit_cast(uint, p2), 0x07060302u);
          uint2 pk; pk.x = d0; pk.y = d1;
          *(uint2*)(myP + (qt * 16 + lr) * PSTR + kt * 16 + qd * 4) = pk;
        }
      }
#pragma unroll
      for (int qt = 0; qt < 2; qt++) {
        const bf16x8 bp = ld8(myP + (qt * 16 + lr) * PSTR + qd * 8);
#pragma unroll
        for (int dt = 0; dt < 4; dt++)
          acc[dt][qt] = __builtin_amdgcn_mfma_f32_16x16x32_bf16(av[dt], bp, acc[dt][qt], 0, 0, 0);
      }
    }

#pragma unroll
    for (int qt = 0; qt < 2; qt++) {
      float s = li[qt];
      s += __shfl_xor(s, 16);
      s += __shfl_xor(s, 32);
      const float inv = 1.f / s;
      const int q = q0 + qt * 16 + lr;
      ushort* orow = O + ((size_t)(b * S_ + q) * D_) + h * DH_ + qd * 4;
#pragma unroll
      for (int dt = 0; dt < 4; dt++) {
        const f32x4 v = acc[dt][qt];
        uint2 pk;
        pk.x = pack2(v[0] * inv, v[1] * inv);
        pk.y = pack2(v[2] * inv, v[3] * inv);
        *(uint2*)(orow + dt * 16) = pk;
      }
    }
  }
}

// ------------------------------------------------------------------- launch
extern "C" void kernel_launch(void* const* d_in, const int* in_sizes, int n_in,
                              void* d_out, int out_size, void* d_ws, size_t ws_size,
                              hipStream_t stream) {
  const float* x  = (const float*)d_in[0];
  const float* Wq = (const float*)d_in[1];
  const float* bq = (const float*)d_in[2];
  const float* Wk = (const float*)d_in[3];
  const float* bk = (const float*)d_in[4];
  const float* Wv = (const float*)d_in[5];
  const float* bv = (const float*)d_in[6];
  const float* Wo = (const float*)d_in[7];
  const float* bo = (const float*)d_in[8];
  float* out = (float*)d_out;

  char* ws = (char*)d_ws;
  ushort* xb   = (ushort*)(ws);                 // x bf16            32 MB
  ushort* qb   = (ushort*)(ws + 33554432);      // Q [B,H,S,dh]      32 MB
  ushort* kb   = (ushort*)(ws + 67108864);      // K [B,H,S,dh]      32 MB
  ushort* vtb  = (ushort*)(ws + 100663296);     // V [B,H,dh,S]      32 MB
  ushort* attn = (ushort*)(ws + 134217728);     // attn out [B,S,d]  32 MB
  ushort* wqb  = (ushort*)(ws + 167772160);     // Wq|Wk|Wv|Wo contiguous
  ushort* wob  = (ushort*)(ws + 174063616);

  cvt4<<<16384, 256, 0, stream>>>(x, xb, 4194304);
  cvtW<<<4096, 256, 0, stream>>>(Wq, Wk, Wv, Wo, wqb);

  gemm_qkv<<<dim3(24, 128), 256, 0, stream>>>(xb, wqb, bq, bk, bv, qb, kb, vtb);

  attn_kernel<<<dim3(4, BH_), 256, 0, stream>>>(qb, kb, vtb, attn);

  gemm_out<<<dim3(8, 128), 256, 0, stream>>>(attn, wob, bo, out);
}